// Round 1
// baseline (351.800 us; speedup 1.0000x reference)
//
#include <hip/hip_runtime.h>

// Problem constants (B,D,H,O) = (16,128,2048,4), W = O*H+O = 8196
#define BB 16
#define DD 128
#define HH 2048
#define OO 4
#define WTOT 8196
#define OHH 8192   // O*H

// ws layout (floats):
//   [0, 32768)      hT[j*16 + b]  : h transposed, j in [0,2048), b in [0,16)
//   [32768, 32832)  u_acc[b*4+o]  : uncertainty accumulator
//   [32832, 32896)  p_acc[b*4+o]  : prediction accumulator

__global__ void k_zero(float* __restrict__ acc) {
    acc[threadIdx.x] = 0.0f;   // 128 threads zero u_acc + p_acc
}

// h = relu(x @ W1^T + b1), stored transposed: hT[j*16+b]
__global__ __launch_bounds__(256) void k_hidden(const float* __restrict__ x,
                                                const float* __restrict__ W1,
                                                const float* __restrict__ b1,
                                                float* __restrict__ hT) {
    __shared__ float xs[DD * BB];   // xs[d*16+b] = x[b][d]  (transposed, conflict-free)
    int tid = threadIdx.x;
    for (int i = tid; i < DD * BB; i += 256) {
        int b = i & 15, d = i >> 4;
        xs[i] = x[b * DD + d];
    }
    __syncthreads();
    int b = tid & 15;
    int j = blockIdx.x * 16 + (tid >> 4);
    const float4* W1v = (const float4*)(W1 + (size_t)j * DD);
    float acc = 0.0f;
#pragma unroll
    for (int dd = 0; dd < DD / 4; ++dd) {
        float4 w = W1v[dd];
        acc = fmaf(xs[(dd * 4 + 0) * 16 + b], w.x, acc);
        acc = fmaf(xs[(dd * 4 + 1) * 16 + b], w.y, acc);
        acc = fmaf(xs[(dd * 4 + 2) * 16 + b], w.z, acc);
        acc = fmaf(xs[(dd * 4 + 3) * 16 + b], w.w, acc);
    }
    acc += b1[j];
    hT[j * 16 + b] = acc > 0.0f ? acc : 0.0f;   // coalesced: index == blk*256 + tid
}

// Main quadratic form: for each o, u[b,o] += h[b,:] @ C_o @ h[b,:]
// Grid: 4 o * 8 col-tiles * 32 k-chunks = 1024 blocks, 256 threads.
// Thread owns column col = ct*256+tid; accumulates acc[b] = sum_k C[k,col]*h[b,k]
// (h[b,k] is block-uniform -> scalar loads), then multiplies by h[b,col],
// block-reduces, atomicAdds 16 floats.
#define KC 64
__global__ __launch_bounds__(256) void k_quad(const float* __restrict__ C,
                                              const float* __restrict__ hT,
                                              float* __restrict__ u_acc) {
    int bid = blockIdx.x;
    int o  = bid & 3;
    int ct = (bid >> 2) & 7;
    int kc = bid >> 5;            // [0, 32)
    int tid = threadIdx.x;
    int col = ct * 256 + tid;     // [0, 2048)
    int base = o * HH;

    const float* Cp = C + (size_t)(base + kc * KC) * WTOT + base + col;
    const float* hk = hT + (size_t)(kc * KC) * 16;   // block-uniform pointer

    float acc[16];
#pragma unroll
    for (int b = 0; b < 16; ++b) acc[b] = 0.0f;

#pragma unroll 4
    for (int k = 0; k < KC; ++k) {
        float c = Cp[(size_t)k * WTOT];              // coalesced 1KB/block per k
#pragma unroll
        for (int b = 0; b < 16; ++b)
            acc[b] = fmaf(hk[k * 16 + b], c, acc[b]); // uniform operand -> s_load
    }

    // multiply by h[b, col] (per-thread) and reduce over the 256 columns
    const float* hc = hT + (size_t)col * 16;
    float v[16];
#pragma unroll
    for (int b = 0; b < 16; ++b) v[b] = acc[b] * hc[b];

#pragma unroll
    for (int b = 0; b < 16; ++b) {
        float s = v[b];
#pragma unroll
        for (int off = 32; off > 0; off >>= 1)
            s += __shfl_down(s, off, 64);
        v[b] = s;   // lane 0 of each wave holds wave sum
    }

    __shared__ float red[4 * 16];
    int lane = tid & 63, wv = tid >> 6;
    if (lane == 0) {
#pragma unroll
        for (int b = 0; b < 16; ++b) red[wv * 16 + b] = v[b];
    }
    __syncthreads();
    if (tid < 16) {
        float s = red[tid] + red[16 + tid] + red[32 + tid] + red[48 + tid];
        atomicAdd(&u_acc[tid * 4 + o], s);
    }
}

// Cross terms (bias row/col of C) + predictions partials.
// Grid: 4 o * 8 k-blocks = 32 blocks; thread = b*16+g handles k = kb*256+i*16+g.
__global__ __launch_bounds__(256) void k_cross(const float* __restrict__ C,
                                               const float* __restrict__ hT,
                                               const float* __restrict__ W2,
                                               float* __restrict__ u_acc,
                                               float* __restrict__ p_acc) {
    int o  = blockIdx.x & 3;
    int kb = blockIdx.x >> 2;    // [0, 8)
    int tid = threadIdx.x;
    int b = tid >> 4, g = tid & 15;
    int base = o * HH;
    float a12 = 0.0f, ap = 0.0f;
#pragma unroll 4
    for (int i = 0; i < 16; ++i) {
        int k = kb * 256 + i * 16 + g;
        float hv = hT[k * 16 + b];
        float c1 = C[(size_t)(base + k) * WTOT + OHH + o];   // column of C (strided)
        float c2 = C[(size_t)(OHH + o) * WTOT + base + k];   // row of C (contiguous)
        float w2 = W2[o * HH + k];
        a12 = fmaf(hv, c1 + c2, a12);
        ap  = fmaf(hv, w2, ap);
    }
#pragma unroll
    for (int off = 8; off > 0; off >>= 1) {
        a12 += __shfl_down(a12, off, 16);
        ap  += __shfl_down(ap, off, 16);
    }
    if (g == 0) {
        atomicAdd(&u_acc[b * OO + o], a12);
        atomicAdd(&p_acc[b * OO + o], ap);
    }
}

// Finalize: out[0..64) = predictions, out[64..128) = uncertainty
__global__ void k_final(const float* __restrict__ C,
                        const float* __restrict__ u_acc,
                        const float* __restrict__ p_acc,
                        const float* __restrict__ b2,
                        float* __restrict__ out) {
    int i = threadIdx.x;   // 64 threads
    int o = i & 3;
    out[i] = p_acc[i] + b2[o];
    out[64 + i] = u_acc[i] + C[(size_t)(OHH + o) * WTOT + OHH + o];
}

extern "C" void kernel_launch(void* const* d_in, const int* in_sizes, int n_in,
                              void* d_out, int out_size, void* d_ws, size_t ws_size,
                              hipStream_t stream) {
    const float* x  = (const float*)d_in[0];
    const float* W1 = (const float*)d_in[1];
    const float* b1 = (const float*)d_in[2];
    const float* W2 = (const float*)d_in[3];
    const float* b2 = (const float*)d_in[4];
    const float* C  = (const float*)d_in[5];
    float* out = (float*)d_out;

    float* hT    = (float*)d_ws;          // 32768 floats
    float* u_acc = hT + HH * BB;          // 64 floats
    float* p_acc = u_acc + 64;            // 64 floats

    hipLaunchKernelGGL(k_zero,   dim3(1),            dim3(128), 0, stream, u_acc);
    hipLaunchKernelGGL(k_hidden, dim3(HH / 16),      dim3(256), 0, stream, x, W1, b1, hT);
    hipLaunchKernelGGL(k_quad,   dim3(4 * 8 * (HH / KC)), dim3(256), 0, stream, C, hT, u_acc);
    hipLaunchKernelGGL(k_cross,  dim3(32),           dim3(256), 0, stream, C, hT, W2, u_acc, p_acc);
    hipLaunchKernelGGL(k_final,  dim3(1),            dim3(64),  0, stream, C, u_acc, p_acc, b2, out);
}